// Round 1
// baseline (2400.029 us; speedup 1.0000x reference)
//
#include <hip/hip_runtime.h>
#include <cstdint>
#include <cstddef>

#define NN 50000
#define NE 800000
#define NG 256
#define NLAY 7

__device__ __forceinline__ float4 ld4(const float* p) { return *(const float4*)p; }

// ---------------- CSR build ----------------
__global__ void k_zero(int* __restrict__ counts, int* __restrict__ gcount) {
  int i = blockIdx.x * 256 + threadIdx.x;
  if (i < NN) counts[i] = 0;
  if (i < NG) gcount[i] = 0;
}

__global__ void k_hist(const int* __restrict__ edge, int* __restrict__ counts) {
  int e = blockIdx.x * 256 + threadIdx.x;
  if (e < NE) atomicAdd(&counts[edge[NE + e]], 1);
}

__global__ void k_ghist(const int* __restrict__ batch, int* __restrict__ gcount) {
  int r = blockIdx.x * 256 + threadIdx.x;
  if (r < NN) atomicAdd(&gcount[batch[r]], 1);
}

__global__ void k_scan_nodes(const int* __restrict__ counts, int* __restrict__ row_ptr,
                             int* __restrict__ cursor) {
  __shared__ int sums[1024];
  int t = threadIdx.x;
  int c0 = t * 49, c1 = min(c0 + 49, NN);
  int s = 0;
  for (int i = c0; i < c1; ++i) s += counts[i];
  sums[t] = s;
  __syncthreads();
  int val = s;
  for (int off = 1; off < 1024; off <<= 1) {
    int o = (t >= off) ? sums[t - off] : 0;
    __syncthreads();
    val += o;
    sums[t] = val;
    __syncthreads();
  }
  int run = val - s;  // exclusive prefix of this thread's chunk
  for (int i = c0; i < c1; ++i) {
    int c = counts[i];
    row_ptr[i] = run;
    cursor[i]  = run;
    run += c;
  }
  if (t == 1023) row_ptr[NN] = run;
}

__global__ void k_gscan(const int* __restrict__ gcount, int* __restrict__ gs) {
  if (threadIdx.x == 0) {
    int run = 0;
    for (int g = 0; g < NG; ++g) { gs[g] = run; run += gcount[g]; }
    gs[NG] = run;
  }
}

__global__ void k_fill(const int* __restrict__ edge, int* __restrict__ cursor,
                       int* __restrict__ csr_src) {
  int e = blockIdx.x * 256 + threadIdx.x;
  if (e < NE) {
    int pos = atomicAdd(&cursor[edge[NE + e]], 1);
    csr_src[pos] = edge[e];
  }
}

// ---------------- Layer kernel 1: aggregate + GEMM(W1) + bias ----------------
__global__ __launch_bounds__(256) void k_l1(
    const float* __restrict__ h, const float* __restrict__ W,
    const float* __restrict__ bias, float* __restrict__ z1,
    const int* __restrict__ row_ptr, const int* __restrict__ csr_src)
{
  __shared__ float zs[64][132];
  __shared__ float wsm[32][128];
  const int tid = threadIdx.x;
  const int m0 = blockIdx.x * 64;
  const int lane = tid & 31;   // col group: cols lane*4..lane*4+3
  const int rgrp = tid >> 5;   // 0..7

  // stage: z = h + sum_{src in CSR[dst]} h[src]  (8 rows per pass, 8 passes)
  for (int pass = 0; pass < 8; ++pass) {
    const int lr = pass * 8 + rgrp;
    const int r = m0 + lr;
    float4 a = make_float4(0.f, 0.f, 0.f, 0.f);
    if (r < NN) {
      a = ld4(h + ((size_t)r << 7) + (lane << 2));
      int e0 = row_ptr[r], e1 = row_ptr[r + 1];
      float ax2 = 0.f, ay2 = 0.f, az2 = 0.f, aw2 = 0.f;
      int e = e0;
      for (; e + 1 < e1; e += 2) {
        int sa = csr_src[e], sb = csr_src[e + 1];
        float4 va = ld4(h + ((size_t)sa << 7) + (lane << 2));
        float4 vb = ld4(h + ((size_t)sb << 7) + (lane << 2));
        a.x += va.x; a.y += va.y; a.z += va.z; a.w += va.w;
        ax2 += vb.x; ay2 += vb.y; az2 += vb.z; aw2 += vb.w;
      }
      if (e < e1) {
        int sa = csr_src[e];
        float4 va = ld4(h + ((size_t)sa << 7) + (lane << 2));
        a.x += va.x; a.y += va.y; a.z += va.z; a.w += va.w;
      }
      a.x += ax2; a.y += ay2; a.z += az2; a.w += aw2;
    }
    *(float4*)&zs[lr][lane << 2] = a;
  }

  // GEMM: [64x128] @ [128x128], micro-tile 8 rows x 4 cols per thread
  float acc[8][4];
  #pragma unroll
  for (int i = 0; i < 8; ++i) { acc[i][0]=0.f; acc[i][1]=0.f; acc[i][2]=0.f; acc[i][3]=0.f; }
  const int tm = tid >> 5, tn = tid & 31;
  for (int k0 = 0; k0 < 128; k0 += 32) {
    __syncthreads();
    #pragma unroll
    for (int j = 0; j < 16; ++j) {
      int idx = tid + j * 256;
      wsm[idx >> 7][idx & 127] = W[((size_t)(k0 + (idx >> 7)) << 7) + (idx & 127)];
    }
    __syncthreads();
    #pragma unroll 4
    for (int k = 0; k < 32; ++k) {
      float4 bv = *(const float4*)&wsm[k][tn << 2];
      #pragma unroll
      for (int i = 0; i < 8; ++i) {
        float av = zs[(tm << 3) + i][k0 + k];
        acc[i][0] = fmaf(av, bv.x, acc[i][0]);
        acc[i][1] = fmaf(av, bv.y, acc[i][1]);
        acc[i][2] = fmaf(av, bv.z, acc[i][2]);
        acc[i][3] = fmaf(av, bv.w, acc[i][3]);
      }
    }
  }
  float4 bb = ld4(bias + (tn << 2));
  #pragma unroll
  for (int i = 0; i < 8; ++i) {
    int r = m0 + (tm << 3) + i;
    if (r < NN) {
      float4 o = make_float4(acc[i][0] + bb.x, acc[i][1] + bb.y,
                             acc[i][2] + bb.z, acc[i][3] + bb.w);
      *(float4*)(z1 + ((size_t)r << 7) + (tn << 2)) = o;
    }
  }
}

// ---------------- BN stats ----------------
__global__ void k_bnstat1(const float* __restrict__ z1, float* __restrict__ psum,
                          float* __restrict__ psq) {
  int col = threadIdx.x;  // 128
  int b = blockIdx.x;     // 256
  int r0 = b * 196, r1 = min(r0 + 196, NN);
  float s = 0.f, q = 0.f;
  for (int r = r0; r < r1; ++r) {
    float v = z1[((size_t)r << 7) + col];
    s += v; q += v * v;
  }
  psum[(b << 7) + col] = s;
  psq[(b << 7) + col] = q;
}

__global__ void k_bnstat2(const float* __restrict__ psum, const float* __restrict__ psq,
                          const float* __restrict__ gamma, const float* __restrict__ beta,
                          float* __restrict__ ab) {
  int col = threadIdx.x;  // 128
  float s = 0.f, q = 0.f;
  for (int b = 0; b < 256; ++b) { s += psum[(b << 7) + col]; q += psq[(b << 7) + col]; }
  float mean = s * (1.f / NN);
  float var = q * (1.f / NN) - mean * mean;
  float rstd = rsqrtf(var + 1e-5f);
  float a = gamma[col] * rstd;
  ab[col] = a;
  ab[128 + col] = beta[col] - mean * a;
}

// ---------------- Layer kernel 2: affine+relu + GEMM(W2) + bias + relu ----------------
__global__ __launch_bounds__(256) void k_l2(
    const float* __restrict__ z1, const float* __restrict__ ab,
    const float* __restrict__ W, const float* __restrict__ bias,
    float* __restrict__ hout)
{
  __shared__ float zs[64][132];
  __shared__ float wsm[32][128];
  const int tid = threadIdx.x;
  const int m0 = blockIdx.x * 64;
  const int lane = tid & 31;
  const int rgrp = tid >> 5;
  float4 aa = ld4(ab + (lane << 2));
  float4 ob = ld4(ab + 128 + (lane << 2));
  for (int pass = 0; pass < 8; ++pass) {
    const int lr = pass * 8 + rgrp;
    const int r = m0 + lr;
    float4 v = make_float4(0.f, 0.f, 0.f, 0.f);
    if (r < NN) v = ld4(z1 + ((size_t)r << 7) + (lane << 2));
    float4 y;
    y.x = fmaxf(fmaf(aa.x, v.x, ob.x), 0.f);
    y.y = fmaxf(fmaf(aa.y, v.y, ob.y), 0.f);
    y.z = fmaxf(fmaf(aa.z, v.z, ob.z), 0.f);
    y.w = fmaxf(fmaf(aa.w, v.w, ob.w), 0.f);
    *(float4*)&zs[lr][lane << 2] = y;
  }

  float acc[8][4];
  #pragma unroll
  for (int i = 0; i < 8; ++i) { acc[i][0]=0.f; acc[i][1]=0.f; acc[i][2]=0.f; acc[i][3]=0.f; }
  const int tm = tid >> 5, tn = tid & 31;
  for (int k0 = 0; k0 < 128; k0 += 32) {
    __syncthreads();
    #pragma unroll
    for (int j = 0; j < 16; ++j) {
      int idx = tid + j * 256;
      wsm[idx >> 7][idx & 127] = W[((size_t)(k0 + (idx >> 7)) << 7) + (idx & 127)];
    }
    __syncthreads();
    #pragma unroll 4
    for (int k = 0; k < 32; ++k) {
      float4 bv = *(const float4*)&wsm[k][tn << 2];
      #pragma unroll
      for (int i = 0; i < 8; ++i) {
        float av = zs[(tm << 3) + i][k0 + k];
        acc[i][0] = fmaf(av, bv.x, acc[i][0]);
        acc[i][1] = fmaf(av, bv.y, acc[i][1]);
        acc[i][2] = fmaf(av, bv.z, acc[i][2]);
        acc[i][3] = fmaf(av, bv.w, acc[i][3]);
      }
    }
  }
  float4 bb = ld4(bias + (tn << 2));
  #pragma unroll
  for (int i = 0; i < 8; ++i) {
    int r = m0 + (tm << 3) + i;
    if (r < NN) {
      float4 o = make_float4(fmaxf(acc[i][0] + bb.x, 0.f), fmaxf(acc[i][1] + bb.y, 0.f),
                             fmaxf(acc[i][2] + bb.z, 0.f), fmaxf(acc[i][3] + bb.w, 0.f));
      *(float4*)(hout + ((size_t)r << 7) + (tn << 2)) = o;
    }
  }
}

// ---------------- Pooling (batch sorted -> contiguous ranges) ----------------
__global__ void k_pool(const float* __restrict__ h, const int* __restrict__ gs,
                       float* __restrict__ pooled, int layer) {
  int g = blockIdx.x, col = threadIdx.x;  // 128 threads
  int r0 = gs[g], r1 = gs[g + 1];
  float s = 0.f, m = 0.f;  // relu outputs >= 0, so 0 is identity for max
  for (int r = r0; r < r1; ++r) {
    float v = h[((size_t)r << 7) + col];
    s += v;
    m = fmaxf(m, v);
  }
  pooled[g * 1792 + layer * 128 + col] = s;
  pooled[g * 1792 + 896 + layer * 128 + col] = m;
}

// ---------------- Final MLP ----------------
// hfin[256,1792] = relu(pooled @ Wl1 + bl1); tile 64x64, micro 4x4
__global__ __launch_bounds__(256) void k_mlp1(
    const float* __restrict__ P, const float* __restrict__ Wl1,
    const float* __restrict__ bl1, float* __restrict__ hfin)
{
  __shared__ float pt[64][33];
  __shared__ float wt[32][64];
  const int tid = threadIdx.x;
  const int n0 = blockIdx.x * 64;
  const int m0 = blockIdx.y * 64;
  const int tm = tid & 15, tn = tid >> 4;
  float acc[4][4];
  #pragma unroll
  for (int i = 0; i < 4; ++i) { acc[i][0]=0.f; acc[i][1]=0.f; acc[i][2]=0.f; acc[i][3]=0.f; }
  for (int k0 = 0; k0 < 1792; k0 += 32) {
    __syncthreads();
    #pragma unroll
    for (int j = 0; j < 8; ++j) {
      int idx = tid + j * 256;  // 2048 = 64 rows x 32 k
      int r = idx >> 5, kk = idx & 31;
      pt[r][kk] = P[(size_t)(m0 + r) * 1792 + k0 + kk];
    }
    #pragma unroll
    for (int j = 0; j < 8; ++j) {
      int idx = tid + j * 256;  // 2048 = 32 k x 64 n
      int kk = idx >> 6, nn = idx & 63;
      wt[kk][nn] = Wl1[(size_t)(k0 + kk) * 1792 + n0 + nn];
    }
    __syncthreads();
    #pragma unroll 4
    for (int k = 0; k < 32; ++k) {
      float4 bv = *(const float4*)&wt[k][tn << 2];
      #pragma unroll
      for (int i = 0; i < 4; ++i) {
        float av = pt[(tm << 2) + i][k];
        acc[i][0] = fmaf(av, bv.x, acc[i][0]);
        acc[i][1] = fmaf(av, bv.y, acc[i][1]);
        acc[i][2] = fmaf(av, bv.z, acc[i][2]);
        acc[i][3] = fmaf(av, bv.w, acc[i][3]);
      }
    }
  }
  float4 bb = ld4(bl1 + n0 + (tn << 2));
  #pragma unroll
  for (int i = 0; i < 4; ++i) {
    int r = m0 + (tm << 2) + i;
    float4 o = make_float4(fmaxf(acc[i][0] + bb.x, 0.f), fmaxf(acc[i][1] + bb.y, 0.f),
                           fmaxf(acc[i][2] + bb.z, 0.f), fmaxf(acc[i][3] + bb.w, 0.f));
    *(float4*)(hfin + (size_t)r * 1792 + n0 + (tn << 2)) = o;
  }
}

__global__ void k_mlp2(const float* __restrict__ hfin, const float* __restrict__ Wl2,
                       const float* __restrict__ bl2, float* __restrict__ out) {
  __shared__ float red[256];
  int g = blockIdx.x, t = threadIdx.x;
  float p = 0.f;
  for (int k = t; k < 1792; k += 256) p += hfin[(size_t)g * 1792 + k] * Wl2[k];
  red[t] = p;
  __syncthreads();
  for (int s = 128; s > 0; s >>= 1) {
    if (t < s) red[t] += red[t + s];
    __syncthreads();
  }
  if (t == 0) {
    float l = red[0] + bl2[0];
    out[g] = 1.f / (1.f + expf(-l));   // sigmoid output
    out[NG + g] = l;                   // raw logit output
  }
}

// ---------------- launch ----------------
extern "C" void kernel_launch(void* const* d_in, const int* in_sizes, int n_in,
                              void* d_out, int out_size, void* d_ws, size_t ws_size,
                              hipStream_t stream) {
  const float* x     = (const float*)d_in[0];
  const int*   edge  = (const int*)d_in[1];
  const int*   batch = (const int*)d_in[2];
  const float* W1    = (const float*)d_in[3];
  const float* b1    = (const float*)d_in[4];
  const float* gamma = (const float*)d_in[5];
  const float* beta  = (const float*)d_in[6];
  const float* W2    = (const float*)d_in[7];
  const float* b2    = (const float*)d_in[8];
  const float* Wl1   = (const float*)d_in[9];
  const float* bl1   = (const float*)d_in[10];
  const float* Wl2   = (const float*)d_in[11];
  const float* bl2   = (const float*)d_in[12];
  float* out = (float*)d_out;

  // workspace layout (ints then floats), ~59 MB total
  int* wsi = (int*)d_ws;
  int* row_ptr = wsi;             // 50048
  int* cursor  = wsi + 50048;     // 50048
  int* counts  = wsi + 100096;    // 50048
  int* csr_src = wsi + 150144;    // 800000
  int* gcount  = wsi + 950144;    // 256
  int* gs      = wsi + 950400;    // 257 (padded to 512)
  float* wsf   = (float*)(wsi + 950912);
  float* A      = wsf;                 // h buffer   [N,128]
  float* Z      = wsf + 6400000;       // z1 buffer  [N,128]
  float* psum   = wsf + 12800000;      // [256,128]
  float* psq    = wsf + 12832768;      // [256,128]
  float* ab     = wsf + 12865536;      // [2,128]
  float* pooled = wsf + 12865792;      // [256,1792]
  float* hfin   = wsf + 13324544;      // [256,1792]

  // CSR + graph offsets (rebuilt every call; ws is poisoned between calls)
  k_zero<<<196, 256, 0, stream>>>(counts, gcount);
  k_hist<<<3125, 256, 0, stream>>>(edge, counts);
  k_ghist<<<196, 256, 0, stream>>>(batch, gcount);
  k_scan_nodes<<<1, 1024, 0, stream>>>(counts, row_ptr, cursor);
  k_gscan<<<1, 64, 0, stream>>>(gcount, gs);
  k_fill<<<3125, 256, 0, stream>>>(edge, cursor, csr_src);

  const float* hin = x;
  for (int i = 0; i < NLAY; ++i) {
    k_l1<<<782, 256, 0, stream>>>(hin, W1 + i * 16384, b1 + i * 128, Z, row_ptr, csr_src);
    k_bnstat1<<<256, 128, 0, stream>>>(Z, psum, psq);
    k_bnstat2<<<1, 128, 0, stream>>>(psum, psq, gamma + i * 128, beta + i * 128, ab);
    k_l2<<<782, 256, 0, stream>>>(Z, ab, W2 + i * 16384, b2 + i * 128, A);
    k_pool<<<256, 128, 0, stream>>>(A, gs, pooled, i);
    hin = A;
  }
  k_mlp1<<<dim3(28, 4), 256, 0, stream>>>(pooled, Wl1, bl1, hfin);
  k_mlp2<<<256, 256, 0, stream>>>(hfin, Wl2, bl2, out);
}

// Round 2
// 1889.372 us; speedup vs baseline: 1.2703x; 1.2703x over previous
//
#include <hip/hip_runtime.h>
#include <cstdint>
#include <cstddef>

#define NN 50000
#define NE 800000
#define NG 256
#define NLAY 7

__device__ __forceinline__ float4 ld4(const float* p) { return *(const float4*)p; }
__device__ __forceinline__ void acc4(float4& a, const float4 b) {
  a.x += b.x; a.y += b.y; a.z += b.z; a.w += b.w;
}

// ---------------- CSR build ----------------
__global__ void k_zero(int* __restrict__ counts, int* __restrict__ gcount) {
  int i = blockIdx.x * 256 + threadIdx.x;
  if (i < NN) counts[i] = 0;
  if (i < NG) gcount[i] = 0;
}

__global__ void k_hist(const int* __restrict__ edge, int* __restrict__ counts) {
  int e = blockIdx.x * 256 + threadIdx.x;
  if (e < NE) atomicAdd(&counts[edge[NE + e]], 1);
}

__global__ void k_ghist(const int* __restrict__ batch, int* __restrict__ gcount) {
  int r = blockIdx.x * 256 + threadIdx.x;
  if (r < NN) atomicAdd(&gcount[batch[r]], 1);
}

__global__ void k_scan_nodes(const int* __restrict__ counts, int* __restrict__ row_ptr,
                             int* __restrict__ cursor) {
  __shared__ int sums[1024];
  int t = threadIdx.x;
  int c0 = t * 49, c1 = min(c0 + 49, NN);
  int s = 0;
  for (int i = c0; i < c1; ++i) s += counts[i];
  sums[t] = s;
  __syncthreads();
  int val = s;
  for (int off = 1; off < 1024; off <<= 1) {
    int o = (t >= off) ? sums[t - off] : 0;
    __syncthreads();
    val += o;
    sums[t] = val;
    __syncthreads();
  }
  int run = val - s;
  for (int i = c0; i < c1; ++i) {
    int c = counts[i];
    row_ptr[i] = run;
    cursor[i]  = run;
    run += c;
  }
  if (t == 1023) row_ptr[NN] = run;
}

__global__ void k_gscan(const int* __restrict__ gcount, int* __restrict__ gs) {
  if (threadIdx.x == 0) {
    int run = 0;
    for (int g = 0; g < NG; ++g) { gs[g] = run; run += gcount[g]; }
    gs[NG] = run;
  }
}

__global__ void k_fill(const int* __restrict__ edge, int* __restrict__ cursor,
                       int* __restrict__ csr_src) {
  int e = blockIdx.x * 256 + threadIdx.x;
  if (e < NE) {
    int pos = atomicAdd(&cursor[edge[NE + e]], 1);
    csr_src[pos] = edge[e];
  }
}

// ---------------- Aggregation: out[r] = h[r] + sum_{s in CSR[r]} h[s] ----------------
// 8 threads per row (16 cols each = 4 float4), 32 rows/block, edge loop unrolled x2
// -> 8 independent b128 loads in flight per thread, no LDS, high occupancy.
__global__ __launch_bounds__(256) void k_agg(
    const float* __restrict__ h, const int* __restrict__ row_ptr,
    const int* __restrict__ csr_src, float* __restrict__ out)
{
  int tid = threadIdx.x;
  int r = blockIdx.x * 32 + (tid >> 3);
  int sub = tid & 7;
  if (r >= NN) return;
  const float* hp = h + ((size_t)r << 7) + (sub << 4);
  float4 a0 = ld4(hp), a1 = ld4(hp + 4), a2 = ld4(hp + 8), a3 = ld4(hp + 12);
  float4 b0 = make_float4(0,0,0,0), b1 = b0, b2 = b0, b3 = b0;
  int e = row_ptr[r], e1 = row_ptr[r + 1];
  for (; e + 1 < e1; e += 2) {
    const float* p0 = h + ((size_t)csr_src[e] << 7) + (sub << 4);
    const float* p1 = h + ((size_t)csr_src[e + 1] << 7) + (sub << 4);
    float4 v0 = ld4(p0), v1 = ld4(p0 + 4), v2 = ld4(p0 + 8), v3 = ld4(p0 + 12);
    float4 w0 = ld4(p1), w1 = ld4(p1 + 4), w2 = ld4(p1 + 8), w3 = ld4(p1 + 12);
    acc4(a0, v0); acc4(a1, v1); acc4(a2, v2); acc4(a3, v3);
    acc4(b0, w0); acc4(b1, w1); acc4(b2, w2); acc4(b3, w3);
  }
  if (e < e1) {
    const float* p0 = h + ((size_t)csr_src[e] << 7) + (sub << 4);
    acc4(a0, ld4(p0)); acc4(a1, ld4(p0 + 4)); acc4(a2, ld4(p0 + 8)); acc4(a3, ld4(p0 + 12));
  }
  acc4(a0, b0); acc4(a1, b1); acc4(a2, b2); acc4(a3, b3);
  float* op = out + ((size_t)r << 7) + (sub << 4);
  *(float4*)op = a0; *(float4*)(op + 4) = a1;
  *(float4*)(op + 8) = a2; *(float4*)(op + 12) = a3;
}

// ---------------- Dense GEMM [N,128]@[128,128], templated pre/post ops ----------------
// PRE: 0 = identity, 1 = affine+relu (ab[0:128]=scale, ab[128:256]=shift)
// POST: 0 = bias only, 1 = bias+relu
template <int PRE, int POST>
__global__ __launch_bounds__(256) void k_gemm(
    const float* __restrict__ in, const float* __restrict__ ab,
    const float* __restrict__ W, const float* __restrict__ bias,
    float* __restrict__ out)
{
  __shared__ float zs[64][132];
  __shared__ float wsm[32][128];
  const int tid = threadIdx.x;
  const int m0 = blockIdx.x * 64;
  const int lane = tid & 31;
  const int rgrp = tid >> 5;
  float4 aa, ob;
  if constexpr (PRE == 1) {
    aa = ld4(ab + (lane << 2));
    ob = ld4(ab + 128 + (lane << 2));
  }
  for (int pass = 0; pass < 8; ++pass) {
    const int lr = pass * 8 + rgrp;
    const int r = m0 + lr;
    float4 v = make_float4(0.f, 0.f, 0.f, 0.f);
    if (r < NN) v = ld4(in + ((size_t)r << 7) + (lane << 2));
    if constexpr (PRE == 1) {
      v.x = fmaxf(fmaf(aa.x, v.x, ob.x), 0.f);
      v.y = fmaxf(fmaf(aa.y, v.y, ob.y), 0.f);
      v.z = fmaxf(fmaf(aa.z, v.z, ob.z), 0.f);
      v.w = fmaxf(fmaf(aa.w, v.w, ob.w), 0.f);
    }
    *(float4*)&zs[lr][lane << 2] = v;
  }

  float acc[8][4];
  #pragma unroll
  for (int i = 0; i < 8; ++i) { acc[i][0]=0.f; acc[i][1]=0.f; acc[i][2]=0.f; acc[i][3]=0.f; }
  const int tm = tid >> 5, tn = tid & 31;
  for (int k0 = 0; k0 < 128; k0 += 32) {
    __syncthreads();
    #pragma unroll
    for (int j = 0; j < 16; ++j) {
      int idx = tid + j * 256;
      wsm[idx >> 7][idx & 127] = W[((size_t)(k0 + (idx >> 7)) << 7) + (idx & 127)];
    }
    __syncthreads();
    #pragma unroll 4
    for (int k = 0; k < 32; ++k) {
      float4 bv = *(const float4*)&wsm[k][tn << 2];
      #pragma unroll
      for (int i = 0; i < 8; ++i) {
        float av = zs[(tm << 3) + i][k0 + k];
        acc[i][0] = fmaf(av, bv.x, acc[i][0]);
        acc[i][1] = fmaf(av, bv.y, acc[i][1]);
        acc[i][2] = fmaf(av, bv.z, acc[i][2]);
        acc[i][3] = fmaf(av, bv.w, acc[i][3]);
      }
    }
  }
  float4 bb = ld4(bias + (tn << 2));
  #pragma unroll
  for (int i = 0; i < 8; ++i) {
    int r = m0 + (tm << 3) + i;
    if (r < NN) {
      float4 o;
      if constexpr (POST == 1) {
        o = make_float4(fmaxf(acc[i][0] + bb.x, 0.f), fmaxf(acc[i][1] + bb.y, 0.f),
                        fmaxf(acc[i][2] + bb.z, 0.f), fmaxf(acc[i][3] + bb.w, 0.f));
      } else {
        o = make_float4(acc[i][0] + bb.x, acc[i][1] + bb.y,
                        acc[i][2] + bb.z, acc[i][3] + bb.w);
      }
      *(float4*)(out + ((size_t)r << 7) + (tn << 2)) = o;
    }
  }
}

// ---------------- BN stats ----------------
__global__ void k_bnstat1(const float* __restrict__ z1, float* __restrict__ psum,
                          float* __restrict__ psq) {
  int col = threadIdx.x;  // 128
  int b = blockIdx.x;     // 512
  int r0 = b * 98, r1 = min(r0 + 98, NN);
  float s = 0.f, q = 0.f;
  for (int r = r0; r < r1; ++r) {
    float v = z1[((size_t)r << 7) + col];
    s += v; q += v * v;
  }
  psum[(b << 7) + col] = s;
  psq[(b << 7) + col] = q;
}

__global__ void k_bnstat2(const float* __restrict__ psum, const float* __restrict__ psq,
                          const float* __restrict__ gamma, const float* __restrict__ beta,
                          float* __restrict__ ab) {
  int col = threadIdx.x;  // 128
  float s = 0.f, q = 0.f;
  for (int b = 0; b < 512; ++b) { s += psum[(b << 7) + col]; q += psq[(b << 7) + col]; }
  float mean = s * (1.f / NN);
  float var = q * (1.f / NN) - mean * mean;
  float rstd = rsqrtf(var + 1e-5f);
  float a = gamma[col] * rstd;
  ab[col] = a;
  ab[128 + col] = beta[col] - mean * a;
}

// ---------------- Pooling (batch sorted -> contiguous ranges) ----------------
__global__ void k_pool(const float* __restrict__ h, const int* __restrict__ gs,
                       float* __restrict__ pooled, int layer) {
  __shared__ float ssum[128], smax[128];
  int g = blockIdx.x;
  int col = threadIdx.x & 127, half = threadIdx.x >> 7;  // 256 threads
  int r0 = gs[g], r1 = gs[g + 1];
  float s = 0.f, m = 0.f;  // relu outputs >= 0, so 0 is identity for max
  for (int r = r0 + half; r < r1; r += 2) {
    float v = h[((size_t)r << 7) + col];
    s += v;
    m = fmaxf(m, v);
  }
  if (half) { ssum[col] = s; smax[col] = m; }
  __syncthreads();
  if (!half) {
    s += ssum[col];
    m = fmaxf(m, smax[col]);
    pooled[g * 1792 + layer * 128 + col] = s;
    pooled[g * 1792 + 896 + layer * 128 + col] = m;
  }
}

// ---------------- Final MLP: split-K partials ----------------
// grid (28 n-tiles, 4 m-tiles, 7 k-chunks); part[kc][256][1792]
__global__ __launch_bounds__(256) void k_mlp1a(
    const float* __restrict__ P, const float* __restrict__ Wl1,
    float* __restrict__ part)
{
  __shared__ float pt[64][33];
  __shared__ float wt[32][64];
  const int tid = threadIdx.x;
  const int n0 = blockIdx.x * 64;
  const int m0 = blockIdx.y * 64;
  const int kc = blockIdx.z;
  const int kbase = kc * 256;
  const int tm = tid & 15, tn = tid >> 4;
  float acc[4][4];
  #pragma unroll
  for (int i = 0; i < 4; ++i) { acc[i][0]=0.f; acc[i][1]=0.f; acc[i][2]=0.f; acc[i][3]=0.f; }
  for (int k0 = kbase; k0 < kbase + 256; k0 += 32) {
    __syncthreads();
    #pragma unroll
    for (int j = 0; j < 8; ++j) {
      int idx = tid + j * 256;  // 2048 = 64 rows x 32 k
      int r = idx >> 5, kk = idx & 31;
      pt[r][kk] = P[(size_t)(m0 + r) * 1792 + k0 + kk];
    }
    #pragma unroll
    for (int j = 0; j < 8; ++j) {
      int idx = tid + j * 256;  // 2048 = 32 k x 64 n
      int kk = idx >> 6, nn = idx & 63;
      wt[kk][nn] = Wl1[(size_t)(k0 + kk) * 1792 + n0 + nn];
    }
    __syncthreads();
    #pragma unroll 4
    for (int k = 0; k < 32; ++k) {
      float4 bv = *(const float4*)&wt[k][tn << 2];
      #pragma unroll
      for (int i = 0; i < 4; ++i) {
        float av = pt[(tm << 2) + i][k];
        acc[i][0] = fmaf(av, bv.x, acc[i][0]);
        acc[i][1] = fmaf(av, bv.y, acc[i][1]);
        acc[i][2] = fmaf(av, bv.z, acc[i][2]);
        acc[i][3] = fmaf(av, bv.w, acc[i][3]);
      }
    }
  }
  float* pp = part + (size_t)kc * 458752;
  #pragma unroll
  for (int i = 0; i < 4; ++i) {
    int r = m0 + (tm << 2) + i;
    *(float4*)(pp + (size_t)r * 1792 + n0 + (tn << 2)) =
        make_float4(acc[i][0], acc[i][1], acc[i][2], acc[i][3]);
  }
}

__global__ void k_mlp1b(const float* __restrict__ part, const float* __restrict__ bl1,
                        float* __restrict__ hfin) {
  int idx = blockIdx.x * 256 + threadIdx.x;  // 458752 total
  int n = idx % 1792;
  float s = bl1[n];
  #pragma unroll
  for (int kc = 0; kc < 7; ++kc) s += part[(size_t)kc * 458752 + idx];
  hfin[idx] = fmaxf(s, 0.f);
}

__global__ void k_mlp2(const float* __restrict__ hfin, const float* __restrict__ Wl2,
                       const float* __restrict__ bl2, float* __restrict__ out) {
  __shared__ float red[256];
  int g = blockIdx.x, t = threadIdx.x;
  float p = 0.f;
  for (int k = t; k < 1792; k += 256) p += hfin[(size_t)g * 1792 + k] * Wl2[k];
  red[t] = p;
  __syncthreads();
  for (int s = 128; s > 0; s >>= 1) {
    if (t < s) red[t] += red[t + s];
    __syncthreads();
  }
  if (t == 0) {
    float l = red[0] + bl2[0];
    out[g] = 1.f / (1.f + expf(-l));   // sigmoid output
    out[NG + g] = l;                   // raw logit output
  }
}

// ---------------- launch ----------------
extern "C" void kernel_launch(void* const* d_in, const int* in_sizes, int n_in,
                              void* d_out, int out_size, void* d_ws, size_t ws_size,
                              hipStream_t stream) {
  const float* x     = (const float*)d_in[0];
  const int*   edge  = (const int*)d_in[1];
  const int*   batch = (const int*)d_in[2];
  const float* W1    = (const float*)d_in[3];
  const float* b1    = (const float*)d_in[4];
  const float* gamma = (const float*)d_in[5];
  const float* beta  = (const float*)d_in[6];
  const float* W2    = (const float*)d_in[7];
  const float* b2    = (const float*)d_in[8];
  const float* Wl1   = (const float*)d_in[9];
  const float* bl1   = (const float*)d_in[10];
  const float* Wl2   = (const float*)d_in[11];
  const float* bl2   = (const float*)d_in[12];
  float* out = (float*)d_out;

  // workspace layout (ints then floats), ~57 MB total
  int* wsi = (int*)d_ws;
  int* row_ptr = wsi;             // 50048
  int* cursor  = wsi + 50048;     // 50048
  int* counts  = wsi + 100096;    // 50048
  int* csr_src = wsi + 150144;    // 800000
  int* gcount  = wsi + 950144;    // 256
  int* gs      = wsi + 950400;    // 257 (padded to 512)
  float* wsf   = (float*)(wsi + 950912);
  float* A      = wsf;                 // [N,128] ping
  float* B      = wsf + 6400000;       // [N,128] pong
  float* psum   = wsf + 12800000;      // [512,128]
  float* psq    = wsf + 12865536;      // [512,128]
  float* ab     = wsf + 12931072;      // [2,128]
  float* pooled = wsf + 12931328;      // [256,1792]
  // MLP scratch aliases B (dead by then): part [7][256][1792] + hfin [256][1792]
  float* part = B;
  float* hfin = B + 3211264;

  // CSR + graph offsets (rebuilt every call; ws is poisoned between calls)
  k_zero<<<196, 256, 0, stream>>>(counts, gcount);
  k_hist<<<3125, 256, 0, stream>>>(edge, counts);
  k_ghist<<<196, 256, 0, stream>>>(batch, gcount);
  k_scan_nodes<<<1, 1024, 0, stream>>>(counts, row_ptr, cursor);
  k_gscan<<<1, 64, 0, stream>>>(gcount, gs);
  k_fill<<<3125, 256, 0, stream>>>(edge, cursor, csr_src);

  for (int i = 0; i < NLAY; ++i) {
    // even i: h_{i-1} (or x) -> agg in A, z1 in B, h_i in A.  odd i: swapped.
    float* P = (i & 1) ? B : A;     // agg dst
    float* Q = (i & 1) ? A : B;     // gemm1 dst (z1)
    const float* hin = (i == 0) ? x : ((i & 1) ? A : B);
    k_agg<<<1563, 256, 0, stream>>>(hin, row_ptr, csr_src, P);
    k_gemm<0, 0><<<782, 256, 0, stream>>>(P, nullptr, W1 + i * 16384, b1 + i * 128, Q);
    k_bnstat1<<<512, 128, 0, stream>>>(Q, psum, psq);
    k_bnstat2<<<1, 128, 0, stream>>>(psum, psq, gamma + i * 128, beta + i * 128, ab);
    k_gemm<1, 1><<<782, 256, 0, stream>>>(Q, ab, W2 + i * 16384, b2 + i * 128, P);
    k_pool<<<256, 256, 0, stream>>>(P, gs, pooled, i);
  }
  k_mlp1a<<<dim3(28, 4, 7), 256, 0, stream>>>(pooled, Wl1, part);
  k_mlp1b<<<1792, 256, 0, stream>>>(part, bl1, hfin);
  k_mlp2<<<256, 256, 0, stream>>>(hfin, Wl2, bl2, out);
}